// Round 1
// baseline (423.441 us; speedup 1.0000x reference)
//
#include <hip/hip_runtime.h>
#include <hip/hip_bf16.h>
#include <math.h>

#define ROWLEN 901
#define NEGENC 0x007FFFFFu   // enc(-inf)

__device__ __forceinline__ unsigned encf(float f) {
    unsigned u = __float_as_uint(f);
    return (u & 0x80000000u) ? ~u : (u | 0x80000000u);
}
__device__ __forceinline__ float decf(unsigned u) {
    return (u & 0x80000000u) ? __uint_as_float(u ^ 0x80000000u)
                             : __uint_as_float(~u);
}

// ---------------------------------------------------------------------------
// K0: compose all linear algebra into small tables.
//   C[256][4]   : rows 0..127 face (feature r), 128..255 body (feature r-128);
//                 cols {a0,a1,b0,b1} where a = ew_top-ew_bot path (dst), b = ew_bot (src)
//   Sp[2][4][4] : spatial (x[:,896..899]) composed, per block
//   Tab[2][3][4]: speaker table, per block
//   Cst[2][4]   : constants (incl. eb folded into 'a' cols)
// ---------------------------------------------------------------------------
__global__ __launch_bounds__(256) void k_compose(
    const float* __restrict__ spkw, const float* __restrict__ spkb,
    const float* __restrict__ spaw, const float* __restrict__ spab,
    const float* __restrict__ f1w, const float* __restrict__ f1b,
    const float* __restrict__ f2w, const float* __restrict__ f2b,
    const float* __restrict__ few, const float* __restrict__ feb,
    const float* __restrict__ g1w, const float* __restrict__ g1b,
    const float* __restrict__ g2w, const float* __restrict__ g2b,
    const float* __restrict__ gew, const float* __restrict__ geb,
    float* __restrict__ C, float* __restrict__ Sp,
    float* __restrict__ Tab, float* __restrict__ Cst)
{
    const int t = threadIdx.x;

    // ---- C: one row per thread ----
    {
        const int blk = t >> 7;          // 0 face, 1 body
        const int fr  = t & 127;         // feature row within block
        const float* w1 = blk ? g1w : f1w;
        const float* w2 = blk ? g2w : f2w;
        const float* ew = blk ? gew : few;
        float acc0 = 0.f, acc1 = 0.f, acc2 = 0.f, acc3 = 0.f;
        #pragma unroll 8
        for (int k = 0; k < 64; ++k) {
            float w = w1[fr * 64 + k] + w2[fr * 64 + k];
            float eb0 = ew[(64 + k) * 2 + 0];
            float eb1 = ew[(64 + k) * 2 + 1];
            float ea0 = ew[k * 2 + 0] - eb0;
            float ea1 = ew[k * 2 + 1] - eb1;
            acc0 += w * ea0; acc1 += w * ea1;
            acc2 += w * eb0; acc3 += w * eb1;
        }
        C[t * 4 + 0] = acc0; C[t * 4 + 1] = acc1;
        C[t * 4 + 2] = acc2; C[t * 4 + 3] = acc3;
    }

    // ---- U (spk path) and V (spa path): 16x2 per (blk, role), one elem/thread ----
    __shared__ float sUV[2][2][2][16][2];  // [isV][blk][role][k16][c]
    {
        const int c    = t & 1;
        const int k16  = (t >> 1) & 15;
        const int role = (t >> 5) & 1;   // 0 = a, 1 = b
        const int blk  = (t >> 6) & 1;
        const int isV  = (t >> 7) & 1;
        const float* w2 = blk ? g2w : f2w;
        const float* ew = blk ? gew : few;
        const int row = (isV ? 144 : 128) + k16;
        float acc = 0.f;
        #pragma unroll 8
        for (int k = 0; k < 64; ++k) {
            float e = role ? ew[(64 + k) * 2 + c]
                           : (ew[k * 2 + c] - ew[(64 + k) * 2 + c]);
            acc += w2[row * 64 + k] * e;
        }
        sUV[isV][blk][role][k16][c] = acc;
    }
    __syncthreads();

    if (t < 24) {  // Tab
        const int blk = t / 12, rem = t % 12;
        const int idx = rem >> 2, q = rem & 3;
        const int role = q >> 1, c = q & 1;
        float acc = 0.f;
        #pragma unroll
        for (int k = 0; k < 16; ++k)
            acc += spkw[idx * 16 + k] * sUV[0][blk][role][k][c];
        Tab[blk * 12 + idx * 4 + q] = acc;
    } else if (t >= 32 && t < 64) {  // Sp
        const int u = t - 32;
        const int blk = u >> 4, rem = u & 15;
        const int r = rem >> 2, q = rem & 3;
        const int role = q >> 1, c = q & 1;
        float acc = 0.f;
        #pragma unroll
        for (int k = 0; k < 16; ++k)
            acc += spaw[r * 16 + k] * sUV[1][blk][role][k][c];
        Sp[blk * 16 + r * 4 + q] = acc;
    } else if (t >= 64 && t < 72) {  // Cst
        const int u = t - 64;
        const int blk = u >> 2, q = u & 3;
        const int role = q >> 1, c = q & 1;
        const float* b1  = blk ? g1b : f1b;
        const float* b2  = blk ? g2b : f2b;
        const float* ew  = blk ? gew : few;
        const float* ebv = blk ? geb : feb;
        float acc = (role == 0) ? ebv[c] : 0.f;   // fold edge-MLP bias into 'a'
        #pragma unroll
        for (int k = 0; k < 16; ++k) {
            acc += spkb[k] * sUV[0][blk][role][k][c];
            acc += spab[k] * sUV[1][blk][role][k][c];
        }
        for (int k = 0; k < 64; ++k) {
            float e = role ? ew[(64 + k) * 2 + c]
                           : (ew[k * 2 + c] - ew[(64 + k) * 2 + c]);
            acc += (b1[k] + b2[k]) * e;
        }
        Cst[blk * 4 + q] = acc;
    }
}

// ---------------------------------------------------------------------------
// K1: one wave per node. Coalesced read of x[node, 0:256] (4 x 256B),
// 8-way dot vs C, butterfly reduce, lane0 adds tail terms + writes
// Adat/Bdat float4 and inits maxbuf to enc(-inf).
// ---------------------------------------------------------------------------
__global__ __launch_bounds__(256) void k_node(
    const float* __restrict__ x,
    const float* __restrict__ C, const float* __restrict__ Sp,
    const float* __restrict__ Tab, const float* __restrict__ Cst,
    float4* __restrict__ Adat, float4* __restrict__ Bdat,
    unsigned* __restrict__ maxbuf, int nnodes)
{
    const int wave = threadIdx.x >> 6;
    const int lane = threadIdx.x & 63;
    const int node = blockIdx.x * 4 + wave;
    if (node >= nnodes) return;

    const float* xr = x + (size_t)node * ROWLEN;

    float p[8] = {0.f, 0.f, 0.f, 0.f, 0.f, 0.f, 0.f, 0.f};
    #pragma unroll
    for (int k = 0; k < 4; ++k) {
        const int e = lane + 64 * k;          // feature index 0..255
        const float v = xr[e];                // coalesced 256B per instr
        const float4 cr = *(const float4*)(C + e * 4);
        const int o = (k >> 1) * 4;           // 0: face, 4: body
        p[o + 0] += v * cr.x; p[o + 1] += v * cr.y;
        p[o + 2] += v * cr.z; p[o + 3] += v * cr.w;
    }

    #pragma unroll
    for (int m = 32; m >= 1; m >>= 1) {
        #pragma unroll
        for (int j = 0; j < 8; ++j)
            p[j] += __shfl_xor(p[j], m, 64);
    }

    if (lane == 0) {
        float xs[4];
        xs[0] = xr[896]; xs[1] = xr[897]; xs[2] = xr[898]; xs[3] = xr[899];
        int idx = (int)fminf(xr[900] - 1.0f, 2.0f);
        idx = idx < 0 ? 0 : (idx > 2 ? 2 : idx);

        float av[4], bv[4];
        #pragma unroll
        for (int blk = 0; blk < 2; ++blk) {
            #pragma unroll
            for (int c = 0; c < 2; ++c) {
                // role a (q = c), role b (q = 2 + c)
                float ea = Tab[blk * 12 + idx * 4 + c] + Cst[blk * 4 + c];
                float eb = Tab[blk * 12 + idx * 4 + 2 + c] + Cst[blk * 4 + 2 + c];
                #pragma unroll
                for (int r = 0; r < 4; ++r) {
                    ea += xs[r] * Sp[blk * 16 + r * 4 + c];
                    eb += xs[r] * Sp[blk * 16 + r * 4 + 2 + c];
                }
                av[blk * 2 + c] = p[blk * 4 + c] + ea;
                bv[blk * 2 + c] = p[blk * 4 + 2 + c] + eb;
            }
        }
        Adat[node] = make_float4(av[0], av[1], av[2], av[3]);
        Bdat[node] = make_float4(bv[0], bv[1], bv[2], bv[3]);
        uint4 init = make_uint4(NEGENC, NEGENC, NEGENC, NEGENC);
        *(uint4*)(maxbuf + (size_t)node * 4) = init;
    }
}

// ---------------------------------------------------------------------------
// K2: per-edge msg + atomicMax into encoded-uint buffer.
// ---------------------------------------------------------------------------
__global__ __launch_bounds__(256) void k_edge(
    const int* __restrict__ ei, const int* __restrict__ ea,
    const float4* __restrict__ Adat, const float4* __restrict__ Bdat,
    unsigned* __restrict__ maxbuf, int nedges)
{
    const int e = blockIdx.x * blockDim.x + threadIdx.x;
    if (e >= nedges) return;
    const int attr = ea[e];
    if (!(attr == 0 || attr == 111)) return;
    const int s = ei[e];
    const int d = ei[nedges + e];
    const float4 a = Adat[d];
    const float4 b = Bdat[s];
    unsigned* mb = maxbuf + (size_t)d * 4;
    atomicMax(mb + 0, encf(a.x + b.x));
    atomicMax(mb + 1, encf(a.y + b.y));
    atomicMax(mb + 2, encf(a.z + b.z));
    atomicMax(mb + 3, encf(a.w + b.w));
}

// ---------------------------------------------------------------------------
// K3: decode, empty-segment -> 0, out = face + body.
// ---------------------------------------------------------------------------
__global__ __launch_bounds__(256) void k_final(
    const unsigned* __restrict__ maxbuf, float* __restrict__ out, int nnodes)
{
    const int n = blockIdx.x * blockDim.x + threadIdx.x;
    if (n >= nnodes) return;
    const uint4 m = *(const uint4*)(maxbuf + (size_t)n * 4);
    float f0 = decf(m.x), f1 = decf(m.y), f2 = decf(m.z), f3 = decf(m.w);
    if (!isfinite(f0)) f0 = 0.f;
    if (!isfinite(f1)) f1 = 0.f;
    if (!isfinite(f2)) f2 = 0.f;
    if (!isfinite(f3)) f3 = 0.f;
    out[(size_t)n * 2 + 0] = f0 + f2;
    out[(size_t)n * 2 + 1] = f1 + f3;
}

extern "C" void kernel_launch(void* const* d_in, const int* in_sizes, int n_in,
                              void* d_out, int out_size, void* d_ws, size_t ws_size,
                              hipStream_t stream) {
    const float* x    = (const float*)d_in[0];
    const int*   ei   = (const int*)d_in[1];
    const int*   ea   = (const int*)d_in[2];
    const float* spkw = (const float*)d_in[3];
    const float* spkb = (const float*)d_in[4];
    const float* spaw = (const float*)d_in[5];
    const float* spab = (const float*)d_in[6];
    const float* f1w  = (const float*)d_in[7];
    const float* f1b  = (const float*)d_in[8];
    const float* f2w  = (const float*)d_in[9];
    const float* f2b  = (const float*)d_in[10];
    const float* few  = (const float*)d_in[11];
    const float* feb  = (const float*)d_in[12];
    const float* g1w  = (const float*)d_in[13];
    const float* g1b  = (const float*)d_in[14];
    const float* g2w  = (const float*)d_in[15];
    const float* g2b  = (const float*)d_in[16];
    const float* gew  = (const float*)d_in[17];
    const float* geb  = (const float*)d_in[18];

    const int N = in_sizes[0] / ROWLEN;
    const int E = in_sizes[2];

    // workspace layout (bytes)
    char* ws = (char*)d_ws;
    float*    C      = (float*)(ws + 0);            // 1024 floats
    float*    Sp     = (float*)(ws + 4096);         // 32 floats
    float*    Tab    = (float*)(ws + 4096 + 128);   // 24 floats
    float*    Cst    = (float*)(ws + 4096 + 256);   // 8 floats
    float4*   Adat   = (float4*)(ws + 16384);                     // N float4
    float4*   Bdat   = (float4*)(ws + 16384 + (size_t)N * 16);    // N float4
    unsigned* maxbuf = (unsigned*)(ws + 16384 + (size_t)N * 32);  // N uint4

    k_compose<<<1, 256, 0, stream>>>(spkw, spkb, spaw, spab,
                                     f1w, f1b, f2w, f2b, few, feb,
                                     g1w, g1b, g2w, g2b, gew, geb,
                                     C, Sp, Tab, Cst);

    k_node<<<(N + 3) / 4, 256, 0, stream>>>(x, C, Sp, Tab, Cst,
                                            Adat, Bdat, maxbuf, N);

    k_edge<<<(E + 255) / 256, 256, 0, stream>>>(ei, ea, Adat, Bdat, maxbuf, E);

    k_final<<<(N + 255) / 256, 256, 0, stream>>>(maxbuf, (float*)d_out, N);
}

// Round 2
// 331.392 us; speedup vs baseline: 1.2778x; 1.2778x over previous
//
#include <hip/hip_runtime.h>
#include <hip/hip_bf16.h>
#include <math.h>

#define ROWLEN 901
#define NEGENC 0x007FFFFFu   // enc(-inf)

__device__ __forceinline__ unsigned encf(float f) {
    unsigned u = __float_as_uint(f);
    return (u & 0x80000000u) ? ~u : (u | 0x80000000u);
}
__device__ __forceinline__ float decf(unsigned u) {
    return (u & 0x80000000u) ? __uint_as_float(u ^ 0x80000000u)
                             : __uint_as_float(~u);
}

// ---------------------------------------------------------------------------
// K0: compose all linear algebra into small tables.
//   C[256][4]   : rows 0..127 face, 128..255 body; cols {a0,a1,b0,b1}
//   Sp[2][4][4], Tab[2][3][4], Cst[2][4]
// LDS-staged edge weights + float4 weight loads: one block, but latency-lean.
// ---------------------------------------------------------------------------
__global__ __launch_bounds__(256) void k_compose(
    const float* __restrict__ spkw, const float* __restrict__ spkb,
    const float* __restrict__ spaw, const float* __restrict__ spab,
    const float* __restrict__ f1w, const float* __restrict__ f1b,
    const float* __restrict__ f2w, const float* __restrict__ f2b,
    const float* __restrict__ few, const float* __restrict__ feb,
    const float* __restrict__ g1w, const float* __restrict__ g1b,
    const float* __restrict__ g2w, const float* __restrict__ g2b,
    const float* __restrict__ gew, const float* __restrict__ geb,
    float* __restrict__ C, float* __restrict__ Sp,
    float* __restrict__ Tab, float* __restrict__ Cst)
{
    const int t = threadIdx.x;
    __shared__ float sEW[2][256];                 // few / gew staged
    __shared__ float sUV[2][2][2][16][2];         // [isV][blk][role][k16][c]
    __shared__ float sBE[8][8];                   // bias-dot partials

    sEW[0][t] = few[t];
    sEW[1][t] = gew[t];
    __syncthreads();

    // ---- C: one row per thread, float4 weight loads, LDS ew ----
    {
        const int blk = t >> 7;
        const int fr  = t & 127;
        const float* w1 = blk ? g1w : f1w;
        const float* w2 = blk ? g2w : f2w;
        const float* e  = sEW[blk];
        float a0 = 0.f, a1 = 0.f, a2 = 0.f, a3 = 0.f;
        #pragma unroll
        for (int k4 = 0; k4 < 16; ++k4) {
            const float4 wa = *(const float4*)(w1 + fr * 64 + k4 * 4);
            const float4 wb = *(const float4*)(w2 + fr * 64 + k4 * 4);
            const float wv[4] = {wa.x + wb.x, wa.y + wb.y, wa.z + wb.z, wa.w + wb.w};
            #pragma unroll
            for (int j = 0; j < 4; ++j) {
                const int k = k4 * 4 + j;
                const float eb0 = e[(64 + k) * 2 + 0];
                const float eb1 = e[(64 + k) * 2 + 1];
                const float ea0 = e[k * 2 + 0] - eb0;
                const float ea1 = e[k * 2 + 1] - eb1;
                a0 += wv[j] * ea0; a1 += wv[j] * ea1;
                a2 += wv[j] * eb0; a3 += wv[j] * eb1;
            }
        }
        C[t * 4 + 0] = a0; C[t * 4 + 1] = a1;
        C[t * 4 + 2] = a2; C[t * 4 + 3] = a3;
    }

    // ---- sUV: 16x2 per (isV, blk, role), float4 w2-row loads ----
    {
        const int c    = t & 1;
        const int k16  = (t >> 1) & 15;
        const int role = (t >> 5) & 1;
        const int blk  = (t >> 6) & 1;
        const int isV  = (t >> 7) & 1;
        const float* w2 = blk ? g2w : f2w;
        const float* e  = sEW[blk];
        const int row = (isV ? 144 : 128) + k16;
        float acc = 0.f;
        #pragma unroll
        for (int k4 = 0; k4 < 16; ++k4) {
            const float4 w = *(const float4*)(w2 + row * 64 + k4 * 4);
            const float wv[4] = {w.x, w.y, w.z, w.w};
            #pragma unroll
            for (int j = 0; j < 4; ++j) {
                const int k = k4 * 4 + j;
                const float ev = role ? e[(64 + k) * 2 + c]
                                      : (e[k * 2 + c] - e[(64 + k) * 2 + c]);
                acc += wv[j] * ev;
            }
        }
        sUV[isV][blk][role][k16][c] = acc;
    }

    // ---- sBE partials: (b1+b2)·e split 8 ways per combo ----
    if (t < 64) {
        const int combo = t >> 3;            // blk<<2 | role<<1 | c
        const int part  = t & 7;
        const int c = combo & 1, role = (combo >> 1) & 1, blk = combo >> 2;
        const float* b1 = blk ? g1b : f1b;
        const float* b2 = blk ? g2b : f2b;
        const float* e  = sEW[blk];
        float acc = 0.f;
        #pragma unroll
        for (int j = 0; j < 8; ++j) {
            const int k = part * 8 + j;
            const float ev = role ? e[(64 + k) * 2 + c]
                                  : (e[k * 2 + c] - e[(64 + k) * 2 + c]);
            acc += (b1[k] + b2[k]) * ev;
        }
        sBE[combo][part] = acc;
    }
    __syncthreads();

    if (t < 24) {  // Tab
        const int blk = t / 12, rem = t % 12;
        const int idx = rem >> 2, q = rem & 3;
        const int role = q >> 1, c = q & 1;
        float acc = 0.f;
        #pragma unroll
        for (int k = 0; k < 16; ++k)
            acc += spkw[idx * 16 + k] * sUV[0][blk][role][k][c];
        Tab[blk * 12 + idx * 4 + q] = acc;
    } else if (t >= 32 && t < 64) {  // Sp
        const int u = t - 32;
        const int blk = u >> 4, rem = u & 15;
        const int r = rem >> 2, q = rem & 3;
        const int role = q >> 1, c = q & 1;
        float acc = 0.f;
        #pragma unroll
        for (int k = 0; k < 16; ++k)
            acc += spaw[r * 16 + k] * sUV[1][blk][role][k][c];
        Sp[blk * 16 + r * 4 + q] = acc;
    } else if (t >= 64 && t < 72) {  // Cst
        const int u = t - 64;
        const int blk = u >> 2, q = u & 3;
        const int role = q >> 1, c = q & 1;
        const float* ebv = blk ? geb : feb;
        float acc = (role == 0) ? ebv[c] : 0.f;
        #pragma unroll
        for (int k = 0; k < 16; ++k) {
            acc += spkb[k] * sUV[0][blk][role][k][c];
            acc += spab[k] * sUV[1][blk][role][k][c];
        }
        #pragma unroll
        for (int p = 0; p < 8; ++p) acc += sBE[u][p];
        Cst[blk * 4 + q] = acc;
    }
}

// ---------------------------------------------------------------------------
// K1: one wave per node. Lanes 0-31 reduce face features, 32-63 body.
// Writes Adat/Bdat, zeroes cnt, inits overflow maxbuf.
// ---------------------------------------------------------------------------
__global__ __launch_bounds__(256) void k_node(
    const float* __restrict__ x,
    const float* __restrict__ C, const float* __restrict__ Sp,
    const float* __restrict__ Tab, const float* __restrict__ Cst,
    float4* __restrict__ Adat, float4* __restrict__ Bdat,
    unsigned* __restrict__ maxbuf, int* __restrict__ cnt, int nnodes)
{
    const int wave = threadIdx.x >> 6;
    const int lane = threadIdx.x & 63;
    const int node = blockIdx.x * 4 + wave;
    if (node >= nnodes) return;

    const float* xr = x + (size_t)node * ROWLEN;
    const int half = lane >> 5;        // 0 face, 1 body
    const int l32  = lane & 31;
    const float* xh = xr + half * 128;
    const float4* C4 = (const float4*)C;

    // issue tail loads early (lane 0 only) to overlap with the reduction
    float xs0 = 0.f, xs1 = 0.f, xs2 = 0.f, xs3 = 0.f, xspk = 0.f;
    if (lane == 0) {
        xs0 = xr[896]; xs1 = xr[897]; xs2 = xr[898]; xs3 = xr[899];
        xspk = xr[900];
    }

    float a0 = 0.f, a1 = 0.f, a2 = 0.f, a3 = 0.f;
    #pragma unroll
    for (int k = 0; k < 4; ++k) {
        const int el = l32 + 32 * k;           // feature within half
        const float v = xh[el];
        const float4 cr = C4[half * 128 + el];
        a0 += v * cr.x; a1 += v * cr.y; a2 += v * cr.z; a3 += v * cr.w;
    }

    #pragma unroll
    for (int m = 16; m >= 1; m >>= 1) {
        a0 += __shfl_xor(a0, m, 64);
        a1 += __shfl_xor(a1, m, 64);
        a2 += __shfl_xor(a2, m, 64);
        a3 += __shfl_xor(a3, m, 64);
    }
    // body sums live on lanes 32-63; pull them to everyone
    const float b0 = __shfl(a0, 32, 64);
    const float b1 = __shfl(a1, 32, 64);
    const float b2 = __shfl(a2, 32, 64);
    const float b3 = __shfl(a3, 32, 64);

    if (lane == 0) {
        const float xs[4] = {xs0, xs1, xs2, xs3};
        int idx = (int)fminf(xspk - 1.0f, 2.0f);
        idx = idx < 0 ? 0 : (idx > 2 ? 2 : idx);

        const float pq[2][4] = {{a0, a1, a2, a3}, {b0, b1, b2, b3}};
        float av[4], bv[4];
        #pragma unroll
        for (int blk = 0; blk < 2; ++blk) {
            #pragma unroll
            for (int c = 0; c < 2; ++c) {
                float ea = Tab[blk * 12 + idx * 4 + c] + Cst[blk * 4 + c];
                float eb = Tab[blk * 12 + idx * 4 + 2 + c] + Cst[blk * 4 + 2 + c];
                #pragma unroll
                for (int r = 0; r < 4; ++r) {
                    ea += xs[r] * Sp[blk * 16 + r * 4 + c];
                    eb += xs[r] * Sp[blk * 16 + r * 4 + 2 + c];
                }
                av[blk * 2 + c] = pq[blk][c] + ea;
                bv[blk * 2 + c] = pq[blk][2 + c] + eb;
            }
        }
        Adat[node] = make_float4(av[0], av[1], av[2], av[3]);
        Bdat[node] = make_float4(bv[0], bv[1], bv[2], bv[3]);
        *(uint4*)(maxbuf + (size_t)node * 4) =
            make_uint4(NEGENC, NEGENC, NEGENC, NEGENC);
        cnt[node] = 0;
    }
}

// ---------------------------------------------------------------------------
// K2: bucket scatter — ONE atomic per edge (vs 4 before). Overflow (rare /
// CAP==0 fallback) uses the encoded atomicMax path on Bdat components.
// ---------------------------------------------------------------------------
__global__ __launch_bounds__(256) void k_scatter(
    const int* __restrict__ ei, const int* __restrict__ ea,
    const float4* __restrict__ Bdat,
    int* __restrict__ cnt, int* __restrict__ bucket,
    unsigned* __restrict__ maxbuf, int nedges, int cap)
{
    const int e = blockIdx.x * blockDim.x + threadIdx.x;
    if (e >= nedges) return;
    const int attr = ea[e];
    if (!(attr == 0 || attr == 111)) return;
    const int s = ei[e];
    const int d = ei[nedges + e];
    const int pos = atomicAdd(cnt + d, 1);
    if (pos < cap) {
        bucket[(size_t)d * cap + pos] = s;
    } else {
        const float4 b = Bdat[s];
        unsigned* mb = maxbuf + (size_t)d * 4;
        atomicMax(mb + 0, encf(b.x));
        atomicMax(mb + 1, encf(b.y));
        atomicMax(mb + 2, encf(b.z));
        atomicMax(mb + 3, encf(b.w));
    }
}

// ---------------------------------------------------------------------------
// K3: per-node gather-max (4 threads/node), fold in overflow buf + Adat,
// empty -> 0, out = face + body.  (a[dst] is segment-constant, so
// segment_max(a+b) = a + segment_max(b).)
// ---------------------------------------------------------------------------
__global__ __launch_bounds__(256) void k_gather(
    const float4* __restrict__ Adat, const float4* __restrict__ Bdat,
    const int* __restrict__ cnt, const int* __restrict__ bucket,
    const unsigned* __restrict__ maxbuf,
    float* __restrict__ out, int nnodes, int cap)
{
    const int t = blockIdx.x * blockDim.x + threadIdx.x;
    const int n = t >> 2, sub = t & 3;
    if (n >= nnodes) return;
    int c = cnt[n]; if (c > cap) c = cap;

    float m0 = -INFINITY, m1 = -INFINITY, m2 = -INFINITY, m3 = -INFINITY;
    const int* row = bucket + (size_t)n * cap;
    for (int i = sub; i < c; i += 4) {
        const int s = row[i];
        const float4 b = Bdat[s];
        m0 = fmaxf(m0, b.x); m1 = fmaxf(m1, b.y);
        m2 = fmaxf(m2, b.z); m3 = fmaxf(m3, b.w);
    }
    #pragma unroll
    for (int msk = 1; msk <= 2; msk <<= 1) {
        m0 = fmaxf(m0, __shfl_xor(m0, msk, 64));
        m1 = fmaxf(m1, __shfl_xor(m1, msk, 64));
        m2 = fmaxf(m2, __shfl_xor(m2, msk, 64));
        m3 = fmaxf(m3, __shfl_xor(m3, msk, 64));
    }
    if (sub == 0) {
        const uint4 ov = *(const uint4*)(maxbuf + (size_t)n * 4);
        m0 = fmaxf(m0, decf(ov.x)); m1 = fmaxf(m1, decf(ov.y));
        m2 = fmaxf(m2, decf(ov.z)); m3 = fmaxf(m3, decf(ov.w));
        const float4 a = Adat[n];
        const float f0 = isfinite(m0) ? a.x + m0 : 0.f;
        const float f1 = isfinite(m1) ? a.y + m1 : 0.f;
        const float f2 = isfinite(m2) ? a.z + m2 : 0.f;
        const float f3 = isfinite(m3) ? a.w + m3 : 0.f;
        out[(size_t)n * 2 + 0] = f0 + f2;
        out[(size_t)n * 2 + 1] = f1 + f3;
    }
}

extern "C" void kernel_launch(void* const* d_in, const int* in_sizes, int n_in,
                              void* d_out, int out_size, void* d_ws, size_t ws_size,
                              hipStream_t stream) {
    const float* x    = (const float*)d_in[0];
    const int*   ei   = (const int*)d_in[1];
    const int*   ea   = (const int*)d_in[2];
    const float* spkw = (const float*)d_in[3];
    const float* spkb = (const float*)d_in[4];
    const float* spaw = (const float*)d_in[5];
    const float* spab = (const float*)d_in[6];
    const float* f1w  = (const float*)d_in[7];
    const float* f1b  = (const float*)d_in[8];
    const float* f2w  = (const float*)d_in[9];
    const float* f2b  = (const float*)d_in[10];
    const float* few  = (const float*)d_in[11];
    const float* feb  = (const float*)d_in[12];
    const float* g1w  = (const float*)d_in[13];
    const float* g1b  = (const float*)d_in[14];
    const float* g2w  = (const float*)d_in[15];
    const float* g2b  = (const float*)d_in[16];
    const float* gew  = (const float*)d_in[17];
    const float* geb  = (const float*)d_in[18];

    const int N = in_sizes[0] / ROWLEN;
    const int E = in_sizes[2];

    // workspace layout
    char* ws = (char*)d_ws;
    float*    C      = (float*)(ws + 0);
    float*    Sp     = (float*)(ws + 4096);
    float*    Tab    = (float*)(ws + 4096 + 128);
    float*    Cst    = (float*)(ws + 4096 + 256);
    size_t off = 16384;
    float4*   Adat   = (float4*)(ws + off);   off += (size_t)N * 16;
    float4*   Bdat   = (float4*)(ws + off);   off += (size_t)N * 16;
    unsigned* maxbuf = (unsigned*)(ws + off); off += (size_t)N * 16;
    int*      cnt    = (int*)(ws + off);      off += (((size_t)N * 4 + 255) / 256) * 256;
    int*      bucket = (int*)(ws + off);
    const size_t remain = ws_size > off ? ws_size - off : 0;
    size_t cap_sz = remain / ((size_t)N * 4);
    int CAP = cap_sz > 64 ? 64 : (int)cap_sz;   // graceful degrade if ws is tight

    k_compose<<<1, 256, 0, stream>>>(spkw, spkb, spaw, spab,
                                     f1w, f1b, f2w, f2b, few, feb,
                                     g1w, g1b, g2w, g2b, gew, geb,
                                     C, Sp, Tab, Cst);

    k_node<<<(N + 3) / 4, 256, 0, stream>>>(x, C, Sp, Tab, Cst,
                                            Adat, Bdat, maxbuf, cnt, N);

    k_scatter<<<(E + 255) / 256, 256, 0, stream>>>(ei, ea, Bdat, cnt, bucket,
                                                   maxbuf, E, CAP);

    k_gather<<<((size_t)N * 4 + 255) / 256, 256, 0, stream>>>(Adat, Bdat, cnt, bucket,
                                                              maxbuf, (float*)d_out, N, CAP);
}

// Round 3
// 321.521 us; speedup vs baseline: 1.3170x; 1.0307x over previous
//
#include <hip/hip_runtime.h>
#include <hip/hip_bf16.h>
#include <math.h>

#define ROWLEN 901
#define NEGENC 0x007FFFFFu   // enc(-inf)
#define CNTSTRIDE 8          // pad cnt to one 32B sector per node (atomic de-contention)

__device__ __forceinline__ unsigned encf(float f) {
    unsigned u = __float_as_uint(f);
    return (u & 0x80000000u) ? ~u : (u | 0x80000000u);
}
__device__ __forceinline__ float decf(unsigned u) {
    return (u & 0x80000000u) ? __uint_as_float(u ^ 0x80000000u)
                             : __uint_as_float(~u);
}

// ---------------------------------------------------------------------------
// K0: compose all linear algebra into small tables. 17 blocks (was 1 — the
// single-block version was ~95us of pure one-CU latency serialization).
//   blocks 0..15 : C[256][4], 16 rows/block, 16 threads/row, shfl reduce
//   block 16     : sUV -> Tab[2][3][4], Sp[2][4][4], Cst[2][4]
// ---------------------------------------------------------------------------
__global__ __launch_bounds__(256) void k_compose(
    const float* __restrict__ spkw, const float* __restrict__ spkb,
    const float* __restrict__ spaw, const float* __restrict__ spab,
    const float* __restrict__ f1w, const float* __restrict__ f1b,
    const float* __restrict__ f2w, const float* __restrict__ f2b,
    const float* __restrict__ few, const float* __restrict__ feb,
    const float* __restrict__ g1w, const float* __restrict__ g1b,
    const float* __restrict__ g2w, const float* __restrict__ g2b,
    const float* __restrict__ gew, const float* __restrict__ geb,
    float* __restrict__ C, float* __restrict__ Sp,
    float* __restrict__ Tab, float* __restrict__ Cst)
{
    const int t = threadIdx.x;

    if (blockIdx.x < 16) {
        // ---- C rows: row = blockIdx*16 + (t>>4); this thread covers k = (t&15)*4 .. +3
        const int row = blockIdx.x * 16 + (t >> 4);
        const int kk  = t & 15;
        const int blk = row >> 7;
        const int fr  = row & 127;
        const float* w1 = blk ? g1w : f1w;
        const float* w2 = blk ? g2w : f2w;
        const float* e  = blk ? gew : few;

        const float4 wa = *(const float4*)(w1 + fr * 64 + kk * 4);
        const float4 wb = *(const float4*)(w2 + fr * 64 + kk * 4);
        const float wv[4] = {wa.x + wb.x, wa.y + wb.y, wa.z + wb.z, wa.w + wb.w};

        float a0 = 0.f, a1 = 0.f, a2 = 0.f, a3 = 0.f;
        #pragma unroll
        for (int j = 0; j < 4; ++j) {
            const int k = kk * 4 + j;
            const float eb0 = e[(64 + k) * 2 + 0];
            const float eb1 = e[(64 + k) * 2 + 1];
            const float ea0 = e[k * 2 + 0] - eb0;
            const float ea1 = e[k * 2 + 1] - eb1;
            a0 += wv[j] * ea0; a1 += wv[j] * ea1;
            a2 += wv[j] * eb0; a3 += wv[j] * eb1;
        }
        // reduce across the 16 threads of this row (aligned 16-lane groups)
        #pragma unroll
        for (int m = 1; m <= 8; m <<= 1) {
            a0 += __shfl_xor(a0, m, 64);
            a1 += __shfl_xor(a1, m, 64);
            a2 += __shfl_xor(a2, m, 64);
            a3 += __shfl_xor(a3, m, 64);
        }
        if (kk == 0) {
            C[row * 4 + 0] = a0; C[row * 4 + 1] = a1;
            C[row * 4 + 2] = a2; C[row * 4 + 3] = a3;
        }
        return;
    }

    // ---- block 16: small tails ----
    __shared__ float sEW[2][256];
    __shared__ float sUV[2][2][2][16][2];  // [isV][blk][role][k16][c]
    __shared__ float sBE[8][8];

    sEW[0][t] = few[t];
    sEW[1][t] = gew[t];
    __syncthreads();

    {   // sUV: 16x2 per (isV, blk, role)
        const int c    = t & 1;
        const int k16  = (t >> 1) & 15;
        const int role = (t >> 5) & 1;
        const int blk  = (t >> 6) & 1;
        const int isV  = (t >> 7) & 1;
        const float* w2 = blk ? g2w : f2w;
        const float* e  = sEW[blk];
        const int row = (isV ? 144 : 128) + k16;
        float acc = 0.f;
        #pragma unroll
        for (int k4 = 0; k4 < 16; ++k4) {
            const float4 w = *(const float4*)(w2 + row * 64 + k4 * 4);
            const float wv[4] = {w.x, w.y, w.z, w.w};
            #pragma unroll
            for (int j = 0; j < 4; ++j) {
                const int k = k4 * 4 + j;
                const float ev = role ? e[(64 + k) * 2 + c]
                                      : (e[k * 2 + c] - e[(64 + k) * 2 + c]);
                acc += wv[j] * ev;
            }
        }
        sUV[isV][blk][role][k16][c] = acc;
    }

    if (t < 64) {  // sBE partials: (b1+b2)·e split 8 ways per combo
        const int combo = t >> 3;            // blk<<2 | role<<1 | c
        const int part  = t & 7;
        const int c = combo & 1, role = (combo >> 1) & 1, blk = combo >> 2;
        const float* b1 = blk ? g1b : f1b;
        const float* b2 = blk ? g2b : f2b;
        const float* e  = sEW[blk];
        float acc = 0.f;
        #pragma unroll
        for (int j = 0; j < 8; ++j) {
            const int k = part * 8 + j;
            const float ev = role ? e[(64 + k) * 2 + c]
                                  : (e[k * 2 + c] - e[(64 + k) * 2 + c]);
            acc += (b1[k] + b2[k]) * ev;
        }
        sBE[combo][part] = acc;
    }
    __syncthreads();

    if (t < 24) {  // Tab
        const int blk = t / 12, rem = t % 12;
        const int idx = rem >> 2, q = rem & 3;
        const int role = q >> 1, c = q & 1;
        float acc = 0.f;
        #pragma unroll
        for (int k = 0; k < 16; ++k)
            acc += spkw[idx * 16 + k] * sUV[0][blk][role][k][c];
        Tab[blk * 12 + idx * 4 + q] = acc;
    } else if (t >= 32 && t < 64) {  // Sp
        const int u = t - 32;
        const int blk = u >> 4, rem = u & 15;
        const int r = rem >> 2, q = rem & 3;
        const int role = q >> 1, c = q & 1;
        float acc = 0.f;
        #pragma unroll
        for (int k = 0; k < 16; ++k)
            acc += spaw[r * 16 + k] * sUV[1][blk][role][k][c];
        Sp[blk * 16 + r * 4 + q] = acc;
    } else if (t >= 64 && t < 72) {  // Cst
        const int u = t - 64;
        const int blk = u >> 2, q = u & 3;
        const int role = q >> 1, c = q & 1;
        const float* ebv = blk ? geb : feb;
        float acc = (role == 0) ? ebv[c] : 0.f;
        #pragma unroll
        for (int k = 0; k < 16; ++k) {
            acc += spkb[k] * sUV[0][blk][role][k][c];
            acc += spab[k] * sUV[1][blk][role][k][c];
        }
        #pragma unroll
        for (int p = 0; p < 8; ++p) acc += sBE[u][p];
        Cst[blk * 4 + q] = acc;
    }
}

// ---------------------------------------------------------------------------
// K1: one wave per node. Lanes 0-31 reduce face features, 32-63 body.
// Writes Adat/Bdat, zeroes cnt (padded), inits overflow maxbuf.
// ---------------------------------------------------------------------------
__global__ __launch_bounds__(256) void k_node(
    const float* __restrict__ x,
    const float* __restrict__ C, const float* __restrict__ Sp,
    const float* __restrict__ Tab, const float* __restrict__ Cst,
    float4* __restrict__ Adat, float4* __restrict__ Bdat,
    unsigned* __restrict__ maxbuf, int* __restrict__ cnt, int nnodes)
{
    const int wave = threadIdx.x >> 6;
    const int lane = threadIdx.x & 63;
    const int node = blockIdx.x * 4 + wave;
    if (node >= nnodes) return;

    const float* xr = x + (size_t)node * ROWLEN;
    const int half = lane >> 5;        // 0 face, 1 body
    const int l32  = lane & 31;
    const float* xh = xr + half * 128;
    const float4* C4 = (const float4*)C;

    float xs0 = 0.f, xs1 = 0.f, xs2 = 0.f, xs3 = 0.f, xspk = 0.f;
    if (lane == 0) {
        xs0 = xr[896]; xs1 = xr[897]; xs2 = xr[898]; xs3 = xr[899];
        xspk = xr[900];
    }

    float a0 = 0.f, a1 = 0.f, a2 = 0.f, a3 = 0.f;
    #pragma unroll
    for (int k = 0; k < 4; ++k) {
        const int el = l32 + 32 * k;
        const float v = xh[el];
        const float4 cr = C4[half * 128 + el];
        a0 += v * cr.x; a1 += v * cr.y; a2 += v * cr.z; a3 += v * cr.w;
    }

    #pragma unroll
    for (int m = 16; m >= 1; m >>= 1) {
        a0 += __shfl_xor(a0, m, 64);
        a1 += __shfl_xor(a1, m, 64);
        a2 += __shfl_xor(a2, m, 64);
        a3 += __shfl_xor(a3, m, 64);
    }
    const float b0 = __shfl(a0, 32, 64);
    const float b1 = __shfl(a1, 32, 64);
    const float b2 = __shfl(a2, 32, 64);
    const float b3 = __shfl(a3, 32, 64);

    if (lane == 0) {
        const float xs[4] = {xs0, xs1, xs2, xs3};
        int idx = (int)fminf(xspk - 1.0f, 2.0f);
        idx = idx < 0 ? 0 : (idx > 2 ? 2 : idx);

        const float pq[2][4] = {{a0, a1, a2, a3}, {b0, b1, b2, b3}};
        float av[4], bv[4];
        #pragma unroll
        for (int blk = 0; blk < 2; ++blk) {
            #pragma unroll
            for (int c = 0; c < 2; ++c) {
                float ea = Tab[blk * 12 + idx * 4 + c] + Cst[blk * 4 + c];
                float eb = Tab[blk * 12 + idx * 4 + 2 + c] + Cst[blk * 4 + 2 + c];
                #pragma unroll
                for (int r = 0; r < 4; ++r) {
                    ea += xs[r] * Sp[blk * 16 + r * 4 + c];
                    eb += xs[r] * Sp[blk * 16 + r * 4 + 2 + c];
                }
                av[blk * 2 + c] = pq[blk][c] + ea;
                bv[blk * 2 + c] = pq[blk][2 + c] + eb;
            }
        }
        Adat[node] = make_float4(av[0], av[1], av[2], av[3]);
        Bdat[node] = make_float4(bv[0], bv[1], bv[2], bv[3]);
        *(uint4*)(maxbuf + (size_t)node * 4) =
            make_uint4(NEGENC, NEGENC, NEGENC, NEGENC);
        cnt[(size_t)node * CNTSTRIDE] = 0;
    }
}

// ---------------------------------------------------------------------------
// K2: bucket scatter — ONE atomicAdd per edge, counters padded to one
// 32B sector each (memory-side atomic units serialize per sector).
// ---------------------------------------------------------------------------
__global__ __launch_bounds__(256) void k_scatter(
    const int* __restrict__ ei, const int* __restrict__ ea,
    const float4* __restrict__ Bdat,
    int* __restrict__ cnt, int* __restrict__ bucket,
    unsigned* __restrict__ maxbuf, int nedges, int cap)
{
    const int e = blockIdx.x * blockDim.x + threadIdx.x;
    if (e >= nedges) return;
    const int attr = ea[e];
    if (!(attr == 0 || attr == 111)) return;
    const int s = ei[e];
    const int d = ei[nedges + e];
    const int pos = atomicAdd(cnt + (size_t)d * CNTSTRIDE, 1);
    if (pos < cap) {
        bucket[(size_t)d * cap + pos] = s;
    } else {
        const float4 b = Bdat[s];
        unsigned* mb = maxbuf + (size_t)d * 4;
        atomicMax(mb + 0, encf(b.x));
        atomicMax(mb + 1, encf(b.y));
        atomicMax(mb + 2, encf(b.z));
        atomicMax(mb + 3, encf(b.w));
    }
}

// ---------------------------------------------------------------------------
// K3: per-node gather-max (4 threads/node), software-pipelined index loads,
// fold in overflow buf + Adat, empty -> 0, out = face + body.
// ---------------------------------------------------------------------------
__global__ __launch_bounds__(256) void k_gather(
    const float4* __restrict__ Adat, const float4* __restrict__ Bdat,
    const int* __restrict__ cnt, const int* __restrict__ bucket,
    const unsigned* __restrict__ maxbuf,
    float* __restrict__ out, int nnodes, int cap)
{
    const int t = blockIdx.x * blockDim.x + threadIdx.x;
    const int n = t >> 2, sub = t & 3;
    if (n >= nnodes) return;
    int c = cnt[(size_t)n * CNTSTRIDE]; if (c > cap) c = cap;

    float m0 = -INFINITY, m1 = -INFINITY, m2 = -INFINITY, m3 = -INFINITY;
    const int* row = bucket + (size_t)n * cap;
    int i = sub;
    int s_next = (i < c) ? row[i] : 0;
    while (i < c) {
        const int s = s_next;
        i += 4;
        if (i < c) s_next = row[i];          // prefetch next index
        const float4 b = Bdat[s];
        m0 = fmaxf(m0, b.x); m1 = fmaxf(m1, b.y);
        m2 = fmaxf(m2, b.z); m3 = fmaxf(m3, b.w);
    }
    #pragma unroll
    for (int msk = 1; msk <= 2; msk <<= 1) {
        m0 = fmaxf(m0, __shfl_xor(m0, msk, 64));
        m1 = fmaxf(m1, __shfl_xor(m1, msk, 64));
        m2 = fmaxf(m2, __shfl_xor(m2, msk, 64));
        m3 = fmaxf(m3, __shfl_xor(m3, msk, 64));
    }
    if (sub == 0) {
        const uint4 ov = *(const uint4*)(maxbuf + (size_t)n * 4);
        m0 = fmaxf(m0, decf(ov.x)); m1 = fmaxf(m1, decf(ov.y));
        m2 = fmaxf(m2, decf(ov.z)); m3 = fmaxf(m3, decf(ov.w));
        const float4 a = Adat[n];
        const float f0 = isfinite(m0) ? a.x + m0 : 0.f;
        const float f1 = isfinite(m1) ? a.y + m1 : 0.f;
        const float f2 = isfinite(m2) ? a.z + m2 : 0.f;
        const float f3 = isfinite(m3) ? a.w + m3 : 0.f;
        out[(size_t)n * 2 + 0] = f0 + f2;
        out[(size_t)n * 2 + 1] = f1 + f3;
    }
}

extern "C" void kernel_launch(void* const* d_in, const int* in_sizes, int n_in,
                              void* d_out, int out_size, void* d_ws, size_t ws_size,
                              hipStream_t stream) {
    const float* x    = (const float*)d_in[0];
    const int*   ei   = (const int*)d_in[1];
    const int*   ea   = (const int*)d_in[2];
    const float* spkw = (const float*)d_in[3];
    const float* spkb = (const float*)d_in[4];
    const float* spaw = (const float*)d_in[5];
    const float* spab = (const float*)d_in[6];
    const float* f1w  = (const float*)d_in[7];
    const float* f1b  = (const float*)d_in[8];
    const float* f2w  = (const float*)d_in[9];
    const float* f2b  = (const float*)d_in[10];
    const float* few  = (const float*)d_in[11];
    const float* feb  = (const float*)d_in[12];
    const float* g1w  = (const float*)d_in[13];
    const float* g1b  = (const float*)d_in[14];
    const float* g2w  = (const float*)d_in[15];
    const float* g2b  = (const float*)d_in[16];
    const float* gew  = (const float*)d_in[17];
    const float* geb  = (const float*)d_in[18];

    const int N = in_sizes[0] / ROWLEN;
    const int E = in_sizes[2];

    // workspace layout
    char* ws = (char*)d_ws;
    float*    C      = (float*)(ws + 0);
    float*    Sp     = (float*)(ws + 4096);
    float*    Tab    = (float*)(ws + 4096 + 128);
    float*    Cst    = (float*)(ws + 4096 + 256);
    size_t off = 16384;
    float4*   Adat   = (float4*)(ws + off);   off += (size_t)N * 16;
    float4*   Bdat   = (float4*)(ws + off);   off += (size_t)N * 16;
    unsigned* maxbuf = (unsigned*)(ws + off); off += (size_t)N * 16;
    int*      cnt    = (int*)(ws + off);      off += (((size_t)N * CNTSTRIDE * 4 + 255) / 256) * 256;
    int*      bucket = (int*)(ws + off);
    const size_t remain = ws_size > off ? ws_size - off : 0;
    size_t cap_sz = remain / ((size_t)N * 4);
    int CAP = cap_sz > 64 ? 64 : (int)cap_sz;   // graceful degrade if ws is tight

    k_compose<<<17, 256, 0, stream>>>(spkw, spkb, spaw, spab,
                                      f1w, f1b, f2w, f2b, few, feb,
                                      g1w, g1b, g2w, g2b, gew, geb,
                                      C, Sp, Tab, Cst);

    k_node<<<(N + 3) / 4, 256, 0, stream>>>(x, C, Sp, Tab, Cst,
                                            Adat, Bdat, maxbuf, cnt, N);

    k_scatter<<<(E + 255) / 256, 256, 0, stream>>>(ei, ea, Bdat, cnt, bucket,
                                                   maxbuf, E, CAP);

    k_gather<<<((size_t)N * 4 + 255) / 256, 256, 0, stream>>>(Adat, Bdat, cnt, bucket,
                                                              maxbuf, (float*)d_out, N, CAP);
}

// Round 4
// 314.754 us; speedup vs baseline: 1.3453x; 1.0215x over previous
//
#include <hip/hip_runtime.h>
#include <hip/hip_bf16.h>
#include <math.h>

#define ROWLEN 901
#define CNTSTRIDE 8          // one 32B sector per counter (atomic de-contention)
#define NB_SC 512            // scatter-role blocks in fused kernel (dispatched first)
#define ZB 96                // zero-role blocks in compose kernel

// ---------------------------------------------------------------------------
// K0: compose all linear algebra into small tables + zero cnt/spillcnt.
//   blocks 0..15   : C[256][4] (16 rows/block, 16 threads/row, shfl reduce)
//   block 16       : sUV -> Tab[2][3][4], Sp[2][4][4], Cst[2][4]
//   blocks 17..17+ZB-1 : zero cnt region + spill counter
// ---------------------------------------------------------------------------
__global__ __launch_bounds__(256) void k_compose(
    const float* __restrict__ spkw, const float* __restrict__ spkb,
    const float* __restrict__ spaw, const float* __restrict__ spab,
    const float* __restrict__ f1w, const float* __restrict__ f1b,
    const float* __restrict__ f2w, const float* __restrict__ f2b,
    const float* __restrict__ few, const float* __restrict__ feb,
    const float* __restrict__ g1w, const float* __restrict__ g1b,
    const float* __restrict__ g2w, const float* __restrict__ g2b,
    const float* __restrict__ gew, const float* __restrict__ geb,
    float* __restrict__ C, float* __restrict__ Sp,
    float* __restrict__ Tab, float* __restrict__ Cst,
    uint4* __restrict__ cntz, int nCntQuads, int* __restrict__ spillcnt)
{
    const int t = threadIdx.x;

    if (blockIdx.x >= 17) {   // ---- zero role ----
        const int zid = blockIdx.x - 17;
        if (zid == 0 && t == 0) *spillcnt = 0;
        const uint4 z = make_uint4(0u, 0u, 0u, 0u);
        for (int i = zid * 256 + t; i < nCntQuads; i += ZB * 256)
            cntz[i] = z;
        return;
    }

    if (blockIdx.x < 16) {
        // ---- C rows: row = blockIdx*16 + (t>>4); thread covers k = (t&15)*4..+3
        const int row = blockIdx.x * 16 + (t >> 4);
        const int kk  = t & 15;
        const int blk = row >> 7;
        const int fr  = row & 127;
        const float* w1 = blk ? g1w : f1w;
        const float* w2 = blk ? g2w : f2w;
        const float* e  = blk ? gew : few;

        const float4 wa = *(const float4*)(w1 + fr * 64 + kk * 4);
        const float4 wb = *(const float4*)(w2 + fr * 64 + kk * 4);
        const float wv[4] = {wa.x + wb.x, wa.y + wb.y, wa.z + wb.z, wa.w + wb.w};

        float a0 = 0.f, a1 = 0.f, a2 = 0.f, a3 = 0.f;
        #pragma unroll
        for (int j = 0; j < 4; ++j) {
            const int k = kk * 4 + j;
            const float eb0 = e[(64 + k) * 2 + 0];
            const float eb1 = e[(64 + k) * 2 + 1];
            const float ea0 = e[k * 2 + 0] - eb0;
            const float ea1 = e[k * 2 + 1] - eb1;
            a0 += wv[j] * ea0; a1 += wv[j] * ea1;
            a2 += wv[j] * eb0; a3 += wv[j] * eb1;
        }
        #pragma unroll
        for (int m = 1; m <= 8; m <<= 1) {
            a0 += __shfl_xor(a0, m, 64);
            a1 += __shfl_xor(a1, m, 64);
            a2 += __shfl_xor(a2, m, 64);
            a3 += __shfl_xor(a3, m, 64);
        }
        if (kk == 0) {
            C[row * 4 + 0] = a0; C[row * 4 + 1] = a1;
            C[row * 4 + 2] = a2; C[row * 4 + 3] = a3;
        }
        return;
    }

    // ---- block 16: small tails ----
    __shared__ float sEW[2][256];
    __shared__ float sUV[2][2][2][16][2];  // [isV][blk][role][k16][c]
    __shared__ float sBE[8][8];

    sEW[0][t] = few[t];
    sEW[1][t] = gew[t];
    __syncthreads();

    {   // sUV: 16x2 per (isV, blk, role)
        const int c    = t & 1;
        const int k16  = (t >> 1) & 15;
        const int role = (t >> 5) & 1;
        const int blk  = (t >> 6) & 1;
        const int isV  = (t >> 7) & 1;
        const float* w2 = blk ? g2w : f2w;
        const float* e  = sEW[blk];
        const int row = (isV ? 144 : 128) + k16;
        float acc = 0.f;
        #pragma unroll
        for (int k4 = 0; k4 < 16; ++k4) {
            const float4 w = *(const float4*)(w2 + row * 64 + k4 * 4);
            const float wv[4] = {w.x, w.y, w.z, w.w};
            #pragma unroll
            for (int j = 0; j < 4; ++j) {
                const int k = k4 * 4 + j;
                const float ev = role ? e[(64 + k) * 2 + c]
                                      : (e[k * 2 + c] - e[(64 + k) * 2 + c]);
                acc += wv[j] * ev;
            }
        }
        sUV[isV][blk][role][k16][c] = acc;
    }

    if (t < 64) {  // sBE partials: (b1+b2)·e split 8 ways per combo
        const int combo = t >> 3;            // blk<<2 | role<<1 | c
        const int part  = t & 7;
        const int c = combo & 1, role = (combo >> 1) & 1, blk = combo >> 2;
        const float* b1 = blk ? g1b : f1b;
        const float* b2 = blk ? g2b : f2b;
        const float* e  = sEW[blk];
        float acc = 0.f;
        #pragma unroll
        for (int j = 0; j < 8; ++j) {
            const int k = part * 8 + j;
            const float ev = role ? e[(64 + k) * 2 + c]
                                  : (e[k * 2 + c] - e[(64 + k) * 2 + c]);
            acc += (b1[k] + b2[k]) * ev;
        }
        sBE[combo][part] = acc;
    }
    __syncthreads();

    if (t < 24) {  // Tab
        const int blk = t / 12, rem = t % 12;
        const int idx = rem >> 2, q = rem & 3;
        const int role = q >> 1, c = q & 1;
        float acc = 0.f;
        #pragma unroll
        for (int k = 0; k < 16; ++k)
            acc += spkw[idx * 16 + k] * sUV[0][blk][role][k][c];
        Tab[blk * 12 + idx * 4 + q] = acc;
    } else if (t >= 32 && t < 64) {  // Sp
        const int u = t - 32;
        const int blk = u >> 4, rem = u & 15;
        const int r = rem >> 2, q = rem & 3;
        const int role = q >> 1, c = q & 1;
        float acc = 0.f;
        #pragma unroll
        for (int k = 0; k < 16; ++k)
            acc += spaw[r * 16 + k] * sUV[1][blk][role][k][c];
        Sp[blk * 16 + r * 4 + q] = acc;
    } else if (t >= 64 && t < 72) {  // Cst
        const int u = t - 64;
        const int blk = u >> 2, q = u & 3;
        const int role = q >> 1, c = q & 1;
        const float* ebv = blk ? geb : feb;
        float acc = (role == 0) ? ebv[c] : 0.f;
        #pragma unroll
        for (int k = 0; k < 16; ++k) {
            acc += spkb[k] * sUV[0][blk][role][k][c];
            acc += spab[k] * sUV[1][blk][role][k][c];
        }
        #pragma unroll
        for (int p = 0; p < 8; ++p) acc += sBE[u][p];
        Cst[blk * 4 + q] = acc;
    }
}

// ---------------------------------------------------------------------------
// K1 fused: blocks [0, NB_SC) do the edge bucket-scatter (atomic-unit-bound),
// blocks [NB_SC, ...) do per-node feature reduction (HBM-BW-bound). The two
// roles use disjoint pipes and overlap on the CUs. Scatter does NOT read
// node output: overflow (degree > CAP, ~never) goes to a spill list sized E.
// ---------------------------------------------------------------------------
__global__ __launch_bounds__(256) void k_fused(
    const float* __restrict__ x,
    const float* __restrict__ C, const float* __restrict__ Sp,
    const float* __restrict__ Tab, const float* __restrict__ Cst,
    float4* __restrict__ Adat, float4* __restrict__ Bdat, int nnodes,
    const int* __restrict__ ei, const int* __restrict__ ea,
    int* __restrict__ cnt, int* __restrict__ bucket,
    int* __restrict__ spillcnt, int* __restrict__ spill,
    int nedges, int cap)
{
    if (blockIdx.x < NB_SC) {
        // ---------------- scatter role ----------------
        for (int e = blockIdx.x * 256 + threadIdx.x; e < nedges; e += NB_SC * 256) {
            const int attr = ea[e];
            if (!(attr == 0 || attr == 111)) continue;
            const int s = ei[e];
            const int d = ei[nedges + e];
            const int pos = atomicAdd(cnt + (size_t)d * CNTSTRIDE, 1);
            if (pos < cap) {
                bucket[(size_t)d * cap + pos] = s;
            } else {
                const int sp = atomicAdd(spillcnt, 1);
                spill[2 * sp + 0] = d;       // spill sized to E: cannot overflow
                spill[2 * sp + 1] = s;
            }
        }
        return;
    }

    // ---------------- node role: one wave per node ----------------
    const int wave = threadIdx.x >> 6;
    const int lane = threadIdx.x & 63;
    const int node = (blockIdx.x - NB_SC) * 4 + wave;
    if (node >= nnodes) return;

    const float* xr = x + (size_t)node * ROWLEN;
    const int half = lane >> 5;        // 0 face, 1 body
    const int l32  = lane & 31;
    const float* xh = xr + half * 128;
    const float4* C4 = (const float4*)C;

    float xs0 = 0.f, xs1 = 0.f, xs2 = 0.f, xs3 = 0.f, xspk = 0.f;
    if (lane == 0) {
        xs0 = xr[896]; xs1 = xr[897]; xs2 = xr[898]; xs3 = xr[899];
        xspk = xr[900];
    }

    float a0 = 0.f, a1 = 0.f, a2 = 0.f, a3 = 0.f;
    #pragma unroll
    for (int k = 0; k < 4; ++k) {
        const int el = l32 + 32 * k;
        const float v = xh[el];
        const float4 cr = C4[half * 128 + el];
        a0 += v * cr.x; a1 += v * cr.y; a2 += v * cr.z; a3 += v * cr.w;
    }

    #pragma unroll
    for (int m = 16; m >= 1; m >>= 1) {
        a0 += __shfl_xor(a0, m, 64);
        a1 += __shfl_xor(a1, m, 64);
        a2 += __shfl_xor(a2, m, 64);
        a3 += __shfl_xor(a3, m, 64);
    }
    const float b0 = __shfl(a0, 32, 64);
    const float b1 = __shfl(a1, 32, 64);
    const float b2 = __shfl(a2, 32, 64);
    const float b3 = __shfl(a3, 32, 64);

    if (lane == 0) {
        const float xs[4] = {xs0, xs1, xs2, xs3};
        int idx = (int)fminf(xspk - 1.0f, 2.0f);
        idx = idx < 0 ? 0 : (idx > 2 ? 2 : idx);

        const float pq[2][4] = {{a0, a1, a2, a3}, {b0, b1, b2, b3}};
        float av[4], bv[4];
        #pragma unroll
        for (int blk = 0; blk < 2; ++blk) {
            #pragma unroll
            for (int c = 0; c < 2; ++c) {
                float ea_ = Tab[blk * 12 + idx * 4 + c] + Cst[blk * 4 + c];
                float eb_ = Tab[blk * 12 + idx * 4 + 2 + c] + Cst[blk * 4 + 2 + c];
                #pragma unroll
                for (int r = 0; r < 4; ++r) {
                    ea_ += xs[r] * Sp[blk * 16 + r * 4 + c];
                    eb_ += xs[r] * Sp[blk * 16 + r * 4 + 2 + c];
                }
                av[blk * 2 + c] = pq[blk][c] + ea_;
                bv[blk * 2 + c] = pq[blk][2 + c] + eb_;
            }
        }
        Adat[node] = make_float4(av[0], av[1], av[2], av[3]);
        Bdat[node] = make_float4(bv[0], bv[1], bv[2], bv[3]);
    }
}

// ---------------------------------------------------------------------------
// K2: per-node gather-max (4 threads/node) over bucket + rare spill list,
// fold in Adat, empty -> 0, out = face + body.
// ---------------------------------------------------------------------------
__global__ __launch_bounds__(256) void k_gather(
    const float4* __restrict__ Adat, const float4* __restrict__ Bdat,
    const int* __restrict__ cnt, const int* __restrict__ bucket,
    const int* __restrict__ spillcnt, const int* __restrict__ spill,
    float* __restrict__ out, int nnodes, int cap)
{
    const int t = blockIdx.x * blockDim.x + threadIdx.x;
    const int n = t >> 2, sub = t & 3;
    if (n >= nnodes) return;
    int c = cnt[(size_t)n * CNTSTRIDE]; if (c > cap) c = cap;

    float m0 = -INFINITY, m1 = -INFINITY, m2 = -INFINITY, m3 = -INFINITY;
    const int* row = bucket + (size_t)n * cap;
    int i = sub;
    int s_next = (i < c) ? row[i] : 0;
    while (i < c) {
        const int s = s_next;
        i += 4;
        if (i < c) s_next = row[i];          // prefetch next index
        const float4 b = Bdat[s];
        m0 = fmaxf(m0, b.x); m1 = fmaxf(m1, b.y);
        m2 = fmaxf(m2, b.z); m3 = fmaxf(m3, b.w);
    }

    const int ns = *spillcnt;                // ~always 0; broadcast L2 hit
    if (ns > 0) {
        for (int j = sub; j < ns; j += 4) {
            if (spill[2 * j] == n) {
                const float4 b = Bdat[spill[2 * j + 1]];
                m0 = fmaxf(m0, b.x); m1 = fmaxf(m1, b.y);
                m2 = fmaxf(m2, b.z); m3 = fmaxf(m3, b.w);
            }
        }
    }

    #pragma unroll
    for (int msk = 1; msk <= 2; msk <<= 1) {
        m0 = fmaxf(m0, __shfl_xor(m0, msk, 64));
        m1 = fmaxf(m1, __shfl_xor(m1, msk, 64));
        m2 = fmaxf(m2, __shfl_xor(m2, msk, 64));
        m3 = fmaxf(m3, __shfl_xor(m3, msk, 64));
    }
    if (sub == 0) {
        const float4 a = Adat[n];
        const float f0 = isfinite(m0) ? a.x + m0 : 0.f;
        const float f1 = isfinite(m1) ? a.y + m1 : 0.f;
        const float f2 = isfinite(m2) ? a.z + m2 : 0.f;
        const float f3 = isfinite(m3) ? a.w + m3 : 0.f;
        out[(size_t)n * 2 + 0] = f0 + f2;
        out[(size_t)n * 2 + 1] = f1 + f3;
    }
}

extern "C" void kernel_launch(void* const* d_in, const int* in_sizes, int n_in,
                              void* d_out, int out_size, void* d_ws, size_t ws_size,
                              hipStream_t stream) {
    const float* x    = (const float*)d_in[0];
    const int*   ei   = (const int*)d_in[1];
    const int*   ea   = (const int*)d_in[2];
    const float* spkw = (const float*)d_in[3];
    const float* spkb = (const float*)d_in[4];
    const float* spaw = (const float*)d_in[5];
    const float* spab = (const float*)d_in[6];
    const float* f1w  = (const float*)d_in[7];
    const float* f1b  = (const float*)d_in[8];
    const float* f2w  = (const float*)d_in[9];
    const float* f2b  = (const float*)d_in[10];
    const float* few  = (const float*)d_in[11];
    const float* feb  = (const float*)d_in[12];
    const float* g1w  = (const float*)d_in[13];
    const float* g1b  = (const float*)d_in[14];
    const float* g2w  = (const float*)d_in[15];
    const float* g2b  = (const float*)d_in[16];
    const float* gew  = (const float*)d_in[17];
    const float* geb  = (const float*)d_in[18];

    const int N = in_sizes[0] / ROWLEN;
    const int E = in_sizes[2];

    // workspace layout
    char* ws = (char*)d_ws;
    float*    C      = (float*)(ws + 0);
    float*    Sp     = (float*)(ws + 4096);
    float*    Tab    = (float*)(ws + 4096 + 128);
    float*    Cst    = (float*)(ws + 4096 + 256);
    size_t off = 16384;
    float4*   Adat   = (float4*)(ws + off);   off += (size_t)N * 16;
    float4*   Bdat   = (float4*)(ws + off);   off += (size_t)N * 16;
    size_t cntBytes  = (((size_t)N * CNTSTRIDE * 4 + 255) / 256) * 256;
    int*      cnt    = (int*)(ws + off);      off += cntBytes;
    int*      spillcnt = (int*)(ws + off);    off += 256;
    int*      spill  = (int*)(ws + off);      off += (((size_t)E * 8 + 255) / 256) * 256;
    int*      bucket = (int*)(ws + off);
    const size_t remain = ws_size > off ? ws_size - off : 0;
    size_t cap_sz = remain / ((size_t)N * 4);
    int CAP = cap_sz > 64 ? 64 : (int)cap_sz;   // graceful degrade if ws is tight

    const int nCntQuads = (int)(cntBytes / 16);

    k_compose<<<17 + ZB, 256, 0, stream>>>(spkw, spkb, spaw, spab,
                                           f1w, f1b, f2w, f2b, few, feb,
                                           g1w, g1b, g2w, g2b, gew, geb,
                                           C, Sp, Tab, Cst,
                                           (uint4*)cnt, nCntQuads, spillcnt);

    const int NB_ND = (N + 3) / 4;
    k_fused<<<NB_SC + NB_ND, 256, 0, stream>>>(x, C, Sp, Tab, Cst,
                                               Adat, Bdat, N,
                                               ei, ea, cnt, bucket,
                                               spillcnt, spill, E, CAP);

    k_gather<<<((size_t)N * 4 + 255) / 256, 256, 0, stream>>>(Adat, Bdat, cnt, bucket,
                                                              spillcnt, spill,
                                                              (float*)d_out, N, CAP);
}

// Round 5
// 307.020 us; speedup vs baseline: 1.3792x; 1.0252x over previous
//
#include <hip/hip_runtime.h>
#include <hip/hip_bf16.h>
#include <math.h>

#define ROWLEN 901
#define NEGENC 0x007FFFFFu   // enc(-inf)
#define GSH 6                // 64 nodes per bin
#define G (1 << GSH)
#define MAXBINS 1024         // supports N <= 65536 (N = 50000 here)
#define NB_A 128             // phase-A binning blocks
#define SUB 32               // slots per (block, bin): Poisson(8) tail-safe
#define BINCAP (NB_A * SUB)  // 4096 entries per bin
#define ZB 96                // zero-role blocks in compose

__device__ __forceinline__ unsigned encf(float f) {
    unsigned u = __float_as_uint(f);
    return (u & 0x80000000u) ? ~u : (u | 0x80000000u);
}
__device__ __forceinline__ float decf(unsigned u) {
    return (u & 0x80000000u) ? __uint_as_float(u ^ 0x80000000u)
                             : __uint_as_float(~u);
}

// ---------------------------------------------------------------------------
// K0: compose all linear algebra into small tables + zero counts/spillcnt.
//   blocks 0..15   : C[256][4] (16 rows/block, 16 threads/row, shfl reduce)
//   block 16       : sUV -> Tab[2][3][4], Sp[2][4][4], Cst[2][4]
//   blocks 17..    : zero counts[NB_A][nbins] + spillcnt
// ---------------------------------------------------------------------------
__global__ __launch_bounds__(256) void k_compose(
    const float* __restrict__ spkw, const float* __restrict__ spkb,
    const float* __restrict__ spaw, const float* __restrict__ spab,
    const float* __restrict__ f1w, const float* __restrict__ f1b,
    const float* __restrict__ f2w, const float* __restrict__ f2b,
    const float* __restrict__ few, const float* __restrict__ feb,
    const float* __restrict__ g1w, const float* __restrict__ g1b,
    const float* __restrict__ g2w, const float* __restrict__ g2b,
    const float* __restrict__ gew, const float* __restrict__ geb,
    float* __restrict__ C, float* __restrict__ Sp,
    float* __restrict__ Tab, float* __restrict__ Cst,
    uint4* __restrict__ zq, int nZeroQuads, int* __restrict__ spillcnt)
{
    const int t = threadIdx.x;

    if (blockIdx.x >= 17) {   // ---- zero role ----
        const int zid = blockIdx.x - 17;
        if (zid == 0 && t == 0) *spillcnt = 0;
        const uint4 z = make_uint4(0u, 0u, 0u, 0u);
        for (int i = zid * 256 + t; i < nZeroQuads; i += ZB * 256)
            zq[i] = z;
        return;
    }

    if (blockIdx.x < 16) {
        // ---- C rows: row = blockIdx*16 + (t>>4); thread covers k = (t&15)*4..+3
        const int row = blockIdx.x * 16 + (t >> 4);
        const int kk  = t & 15;
        const int blk = row >> 7;
        const int fr  = row & 127;
        const float* w1 = blk ? g1w : f1w;
        const float* w2 = blk ? g2w : f2w;
        const float* e  = blk ? gew : few;

        const float4 wa = *(const float4*)(w1 + fr * 64 + kk * 4);
        const float4 wb = *(const float4*)(w2 + fr * 64 + kk * 4);
        const float wv[4] = {wa.x + wb.x, wa.y + wb.y, wa.z + wb.z, wa.w + wb.w};

        float a0 = 0.f, a1 = 0.f, a2 = 0.f, a3 = 0.f;
        #pragma unroll
        for (int j = 0; j < 4; ++j) {
            const int k = kk * 4 + j;
            const float eb0 = e[(64 + k) * 2 + 0];
            const float eb1 = e[(64 + k) * 2 + 1];
            const float ea0 = e[k * 2 + 0] - eb0;
            const float ea1 = e[k * 2 + 1] - eb1;
            a0 += wv[j] * ea0; a1 += wv[j] * ea1;
            a2 += wv[j] * eb0; a3 += wv[j] * eb1;
        }
        #pragma unroll
        for (int m = 1; m <= 8; m <<= 1) {
            a0 += __shfl_xor(a0, m, 64);
            a1 += __shfl_xor(a1, m, 64);
            a2 += __shfl_xor(a2, m, 64);
            a3 += __shfl_xor(a3, m, 64);
        }
        if (kk == 0) {
            C[row * 4 + 0] = a0; C[row * 4 + 1] = a1;
            C[row * 4 + 2] = a2; C[row * 4 + 3] = a3;
        }
        return;
    }

    // ---- block 16: small tails ----
    __shared__ float sEW[2][256];
    __shared__ float sUV[2][2][2][16][2];  // [isV][blk][role][k16][c]
    __shared__ float sBE[8][8];

    sEW[0][t] = few[t];
    sEW[1][t] = gew[t];
    __syncthreads();

    {   // sUV: 16x2 per (isV, blk, role)
        const int c    = t & 1;
        const int k16  = (t >> 1) & 15;
        const int role = (t >> 5) & 1;
        const int blk  = (t >> 6) & 1;
        const int isV  = (t >> 7) & 1;
        const float* w2 = blk ? g2w : f2w;
        const float* e  = sEW[blk];
        const int row = (isV ? 144 : 128) + k16;
        float acc = 0.f;
        #pragma unroll
        for (int k4 = 0; k4 < 16; ++k4) {
            const float4 w = *(const float4*)(w2 + row * 64 + k4 * 4);
            const float wv[4] = {w.x, w.y, w.z, w.w};
            #pragma unroll
            for (int j = 0; j < 4; ++j) {
                const int k = k4 * 4 + j;
                const float ev = role ? e[(64 + k) * 2 + c]
                                      : (e[k * 2 + c] - e[(64 + k) * 2 + c]);
                acc += wv[j] * ev;
            }
        }
        sUV[isV][blk][role][k16][c] = acc;
    }

    if (t < 64) {  // sBE partials: (b1+b2)·e split 8 ways per combo
        const int combo = t >> 3;            // blk<<2 | role<<1 | c
        const int part  = t & 7;
        const int c = combo & 1, role = (combo >> 1) & 1, blk = combo >> 2;
        const float* b1 = blk ? g1b : f1b;
        const float* b2 = blk ? g2b : f2b;
        const float* e  = sEW[blk];
        float acc = 0.f;
        #pragma unroll
        for (int j = 0; j < 8; ++j) {
            const int k = part * 8 + j;
            const float ev = role ? e[(64 + k) * 2 + c]
                                  : (e[k * 2 + c] - e[(64 + k) * 2 + c]);
            acc += (b1[k] + b2[k]) * ev;
        }
        sBE[combo][part] = acc;
    }
    __syncthreads();

    if (t < 24) {  // Tab
        const int blk = t / 12, rem = t % 12;
        const int idx = rem >> 2, q = rem & 3;
        const int role = q >> 1, c = q & 1;
        float acc = 0.f;
        #pragma unroll
        for (int k = 0; k < 16; ++k)
            acc += spkw[idx * 16 + k] * sUV[0][blk][role][k][c];
        Tab[blk * 12 + idx * 4 + q] = acc;
    } else if (t >= 32 && t < 64) {  // Sp
        const int u = t - 32;
        const int blk = u >> 4, rem = u & 15;
        const int r = rem >> 2, q = rem & 3;
        const int role = q >> 1, c = q & 1;
        float acc = 0.f;
        #pragma unroll
        for (int k = 0; k < 16; ++k)
            acc += spaw[r * 16 + k] * sUV[1][blk][role][k][c];
        Sp[blk * 16 + r * 4 + q] = acc;
    } else if (t >= 64 && t < 72) {  // Cst
        const int u = t - 64;
        const int blk = u >> 2, q = u & 3;
        const int role = q >> 1, c = q & 1;
        const float* ebv = blk ? geb : feb;
        float acc = (role == 0) ? ebv[c] : 0.f;
        #pragma unroll
        for (int k = 0; k < 16; ++k) {
            acc += spkb[k] * sUV[0][blk][role][k][c];
            acc += spab[k] * sUV[1][blk][role][k][c];
        }
        #pragma unroll
        for (int p = 0; p < 8; ++p) acc += sBE[u][p];
        Cst[blk * 4 + q] = acc;
    }
}

// ---------------------------------------------------------------------------
// K1 fused:
//   blocks [0, NB_A)  : phase-A edge binning — LDS counters, deterministic
//                       per-(block,bin) slices, ZERO global atomics hot path.
//                       entry = src | (dst&63)<<20  (4B; needs N <= 2^20)
//   blocks [NB_A, ...) : per-node feature reduction (HBM-BW-bound), writes
//                       Adat/Bdat. Roles overlap on the CUs.
// ---------------------------------------------------------------------------
__global__ __launch_bounds__(256) void k_fused(
    const float* __restrict__ x,
    const float* __restrict__ C, const float* __restrict__ Sp,
    const float* __restrict__ Tab, const float* __restrict__ Cst,
    float4* __restrict__ Adat, float4* __restrict__ Bdat, int nnodes,
    const int* __restrict__ ei, const int* __restrict__ ea,
    int* __restrict__ binData, int* __restrict__ counts,
    int* __restrict__ spillcnt, int* __restrict__ spill,
    int nedges, int nbins)
{
    __shared__ int sCnt[MAXBINS];

    if (blockIdx.x < NB_A) {
        // ---------------- phase-A binning role ----------------
        for (int i = threadIdx.x; i < nbins; i += 256) sCnt[i] = 0;
        __syncthreads();
        const int chunk = (nedges + NB_A - 1) / NB_A;
        const int e0 = blockIdx.x * chunk;
        const int e1 = min(e0 + chunk, nedges);
        for (int e = e0 + threadIdx.x; e < e1; e += 256) {
            const int attr = ea[e];
            if (!(attr == 0 || attr == 111)) continue;
            const int s = ei[e];
            const int d = ei[nedges + e];
            const int bin = d >> GSH;
            const int slot = atomicAdd(&sCnt[bin], 1);   // LDS atomic: cheap
            if (slot < SUB) {
                binData[(size_t)bin * BINCAP + blockIdx.x * SUB + slot] =
                    s | ((d & (G - 1)) << 20);
            } else {                                     // ~never (Poisson(8))
                const int sp = atomicAdd(spillcnt, 1);
                spill[2 * sp + 0] = d;
                spill[2 * sp + 1] = s;
            }
        }
        __syncthreads();
        for (int i = threadIdx.x; i < nbins; i += 256)
            counts[blockIdx.x * nbins + i] = sCnt[i];    // dense store
        return;
    }

    // ---------------- node role: one wave per node ----------------
    const int wave = threadIdx.x >> 6;
    const int lane = threadIdx.x & 63;
    const int node = (blockIdx.x - NB_A) * 4 + wave;
    if (node >= nnodes) return;

    const float* xr = x + (size_t)node * ROWLEN;
    const int half = lane >> 5;        // 0 face, 1 body
    const int l32  = lane & 31;
    const float* xh = xr + half * 128;
    const float4* C4 = (const float4*)C;

    float xs0 = 0.f, xs1 = 0.f, xs2 = 0.f, xs3 = 0.f, xspk = 0.f;
    if (lane == 0) {
        xs0 = xr[896]; xs1 = xr[897]; xs2 = xr[898]; xs3 = xr[899];
        xspk = xr[900];
    }

    float a0 = 0.f, a1 = 0.f, a2 = 0.f, a3 = 0.f;
    #pragma unroll
    for (int k = 0; k < 4; ++k) {
        const int el = l32 + 32 * k;
        const float v = xh[el];
        const float4 cr = C4[half * 128 + el];
        a0 += v * cr.x; a1 += v * cr.y; a2 += v * cr.z; a3 += v * cr.w;
    }

    #pragma unroll
    for (int m = 16; m >= 1; m >>= 1) {
        a0 += __shfl_xor(a0, m, 64);
        a1 += __shfl_xor(a1, m, 64);
        a2 += __shfl_xor(a2, m, 64);
        a3 += __shfl_xor(a3, m, 64);
    }
    const float b0 = __shfl(a0, 32, 64);
    const float b1 = __shfl(a1, 32, 64);
    const float b2 = __shfl(a2, 32, 64);
    const float b3 = __shfl(a3, 32, 64);

    if (lane == 0) {
        const float xs[4] = {xs0, xs1, xs2, xs3};
        int idx = (int)fminf(xspk - 1.0f, 2.0f);
        idx = idx < 0 ? 0 : (idx > 2 ? 2 : idx);

        const float pq[2][4] = {{a0, a1, a2, a3}, {b0, b1, b2, b3}};
        float av[4], bv[4];
        #pragma unroll
        for (int blk = 0; blk < 2; ++blk) {
            #pragma unroll
            for (int c = 0; c < 2; ++c) {
                float ea_ = Tab[blk * 12 + idx * 4 + c] + Cst[blk * 4 + c];
                float eb_ = Tab[blk * 12 + idx * 4 + 2 + c] + Cst[blk * 4 + 2 + c];
                #pragma unroll
                for (int r = 0; r < 4; ++r) {
                    ea_ += xs[r] * Sp[blk * 16 + r * 4 + c];
                    eb_ += xs[r] * Sp[blk * 16 + r * 4 + 2 + c];
                }
                av[blk * 2 + c] = pq[blk][c] + ea_;
                bv[blk * 2 + c] = pq[blk][2 + c] + eb_;
            }
        }
        Adat[node] = make_float4(av[0], av[1], av[2], av[3]);
        Bdat[node] = make_float4(bv[0], bv[1], bv[2], bv[3]);
    }
}

// ---------------------------------------------------------------------------
// K2: one block per bin (64 dst nodes). Max Bdat[src] over the bin's entries
// into LDS (encoded-uint atomicMax), fold spill (~never) + Adat, write out.
// Replaces the old bucket+gather entirely.
// ---------------------------------------------------------------------------
__global__ __launch_bounds__(256) void k_final(
    const float4* __restrict__ Adat, const float4* __restrict__ Bdat,
    const int* __restrict__ binData, const int* __restrict__ counts,
    const int* __restrict__ spillcnt, const int* __restrict__ spill,
    float* __restrict__ out, int nnodes, int nbins)
{
    const int bin = blockIdx.x;
    const int t = threadIdx.x;
    __shared__ unsigned sMax[G * 4];
    __shared__ int sC[NB_A];
    __shared__ int sNs;

    if (t < G * 4) sMax[t] = NEGENC;
    if (t < NB_A) sC[t] = counts[t * nbins + bin];
    if (t == 0) sNs = *spillcnt;
    __syncthreads();

    // NB_A slices; 32 slices per round x 8 threads each
    #pragma unroll
    for (int r = 0; r < NB_A / 32; ++r) {
        const int slice = r * 32 + (t >> 3);
        int c = sC[slice]; if (c > SUB) c = SUB;
        const int* base = binData + (size_t)bin * BINCAP + slice * SUB;
        for (int j = (t & 7); j < c; j += 8) {
            const int entry = base[j];
            const int s  = entry & 0xFFFFF;
            const int dl = (entry >> 20) & (G - 1);
            const float4 b = Bdat[s];                    // L2-resident (800KB)
            atomicMax(&sMax[dl * 4 + 0], encf(b.x));
            atomicMax(&sMax[dl * 4 + 1], encf(b.y));
            atomicMax(&sMax[dl * 4 + 2], encf(b.z));
            atomicMax(&sMax[dl * 4 + 3], encf(b.w));
        }
    }

    if (sNs > 0) {   // rare overflow path
        const int lo = bin << GSH, hi = lo + G;
        for (int j = t; j < sNs; j += 256) {
            const int d = spill[2 * j];
            if (d >= lo && d < hi) {
                const float4 b = Bdat[spill[2 * j + 1]];
                const int dl = d - lo;
                atomicMax(&sMax[dl * 4 + 0], encf(b.x));
                atomicMax(&sMax[dl * 4 + 1], encf(b.y));
                atomicMax(&sMax[dl * 4 + 2], encf(b.z));
                atomicMax(&sMax[dl * 4 + 3], encf(b.w));
            }
        }
    }
    __syncthreads();

    if (t < G) {
        const int n = (bin << GSH) + t;
        if (n < nnodes) {
            const float m0 = decf(sMax[t * 4 + 0]);
            const float m1 = decf(sMax[t * 4 + 1]);
            const float m2 = decf(sMax[t * 4 + 2]);
            const float m3 = decf(sMax[t * 4 + 3]);
            const float4 a = Adat[n];
            const float f0 = isfinite(m0) ? a.x + m0 : 0.f;
            const float f1 = isfinite(m1) ? a.y + m1 : 0.f;
            const float f2 = isfinite(m2) ? a.z + m2 : 0.f;
            const float f3 = isfinite(m3) ? a.w + m3 : 0.f;
            out[(size_t)n * 2 + 0] = f0 + f2;
            out[(size_t)n * 2 + 1] = f1 + f3;
        }
    }
}

extern "C" void kernel_launch(void* const* d_in, const int* in_sizes, int n_in,
                              void* d_out, int out_size, void* d_ws, size_t ws_size,
                              hipStream_t stream) {
    const float* x    = (const float*)d_in[0];
    const int*   ei   = (const int*)d_in[1];
    const int*   ea   = (const int*)d_in[2];
    const float* spkw = (const float*)d_in[3];
    const float* spkb = (const float*)d_in[4];
    const float* spaw = (const float*)d_in[5];
    const float* spab = (const float*)d_in[6];
    const float* f1w  = (const float*)d_in[7];
    const float* f1b  = (const float*)d_in[8];
    const float* f2w  = (const float*)d_in[9];
    const float* f2b  = (const float*)d_in[10];
    const float* few  = (const float*)d_in[11];
    const float* feb  = (const float*)d_in[12];
    const float* g1w  = (const float*)d_in[13];
    const float* g1b  = (const float*)d_in[14];
    const float* g2w  = (const float*)d_in[15];
    const float* g2b  = (const float*)d_in[16];
    const float* gew  = (const float*)d_in[17];
    const float* geb  = (const float*)d_in[18];

    const int N = in_sizes[0] / ROWLEN;
    const int E = in_sizes[2];
    const int nbins = (N + G - 1) >> GSH;   // 782 for N=50000 (<= MAXBINS)

    // workspace layout
    char* ws = (char*)d_ws;
    float*    C      = (float*)(ws + 0);
    float*    Sp     = (float*)(ws + 4096);
    float*    Tab    = (float*)(ws + 4096 + 128);
    float*    Cst    = (float*)(ws + 4096 + 256);
    size_t off = 16384;
    float4*   Adat   = (float4*)(ws + off);   off += (size_t)N * 16;
    float4*   Bdat   = (float4*)(ws + off);   off += (size_t)N * 16;
    size_t countsBytes = (((size_t)NB_A * nbins * 4 + 255) / 256) * 256;
    int*      counts = (int*)(ws + off);      off += countsBytes;
    int*      spillcnt = (int*)(ws + off);    off += 256;
    int*      spill  = (int*)(ws + off);      off += (((size_t)E * 8 + 255) / 256) * 256;
    int*      binData = (int*)(ws + off);     // nbins * BINCAP * 4 bytes (~12.5 MB)

    const int nZeroQuads = (int)(countsBytes / 16);

    k_compose<<<17 + ZB, 256, 0, stream>>>(spkw, spkb, spaw, spab,
                                           f1w, f1b, f2w, f2b, few, feb,
                                           g1w, g1b, g2w, g2b, gew, geb,
                                           C, Sp, Tab, Cst,
                                           (uint4*)counts, nZeroQuads, spillcnt);

    const int NB_ND = (N + 3) / 4;
    k_fused<<<NB_A + NB_ND, 256, 0, stream>>>(x, C, Sp, Tab, Cst,
                                              Adat, Bdat, N,
                                              ei, ea, binData, counts,
                                              spillcnt, spill, E, nbins);

    k_final<<<nbins, 256, 0, stream>>>(Adat, Bdat, binData, counts,
                                       spillcnt, spill,
                                       (float*)d_out, N, nbins);
}